// Round 5
// baseline (240.523 us; speedup 1.0000x reference)
//
#include <hip/hip_runtime.h>
#include <math.h>

#define N_SP 3136
#define BN_EPS 1e-5f

typedef __attribute__((ext_vector_type(8))) short short8;
typedef __attribute__((ext_vector_type(4))) float f32x4;

// ws layout (float elements)
#define QK_SZ   (16*2*384*N_SP)          // 38,535,168
#define KVP_OFF (QK_SZ)
#define KVP_SZ  (16*6*7*64*80)           // 3,440,640  ([d][80]: cols 0..63 kv, col 64 = sum_k)
#define KVT_OFF (KVP_OFF + KVP_SZ)       // 2 bf16 planes, 96*80*64 ushorts each
#define KVT_FSZ (2*96*80*64/2)           // 491,520 floats backing the 2 ushort planes
#define WH_OFF  (KVT_OFF + KVT_FSZ)
#define WSPLIT_N (2*384*192)             // 147456 elements

__device__ __forceinline__ void bsplit(float f, ushort& h, ushort& l) {
    uint u = __float_as_uint(f);
    uint hr = (u + 0x7FFFu + ((u >> 16) & 1u)) >> 16;
    h = (ushort)hr;
    float fh = __uint_as_float(hr << 16);
    float fl = f - fh;
    uint v = __float_as_uint(fl);
    l = (ushort)((v + 0x7FFFu + ((v >> 16) & 1u)) >> 16);
}

// ---------------- P0: split qk_w into bf16 hi/lo planes ([g][o][k], k contiguous)
__global__ __launch_bounds__(256) void p0_wsplit(
    const float* __restrict__ qk_w, ushort* __restrict__ wh, ushort* __restrict__ wl)
{
    int idx = blockIdx.x * 256 + threadIdx.x;
    if (idx >= WSPLIT_N) return;
    ushort h, l;
    bsplit(qk_w[idx], h, l);
    wh[idx] = h;
    wl[idx] = l;
}

// ---------------- K1: qk GEMM via bf16-split MFMA (unchanged).
__global__ __launch_bounds__(256) void k1_qk_mfma(
    const float* __restrict__ x, const ushort* __restrict__ wh, const ushort* __restrict__ wl,
    const float* __restrict__ gamma, const float* __restrict__ beta,
    const float* __restrict__ mean, const float* __restrict__ var,
    float* __restrict__ qk_out)
{
    __shared__ __align__(16) ushort Ah[8192];
    __shared__ __align__(16) ushort Al[8192];
    __shared__ __align__(16) ushort Bh[4096];
    __shared__ __align__(16) ushort Bl[4096];

    const int bx = blockIdx.x;           // 49 n-tiles
    const int by = blockIdx.y;           // 3 o-tiles (128 each)
    const int bz = blockIdx.z;           // b*2+g
    const int b = bz >> 1, gg = bz & 1;
    const int t = threadIdx.x;
    const int lane = t & 63, wv = t >> 6;
    const int wr = wv >> 1, wc = wv & 1;
    const int lg = lane >> 4, l15 = lane & 15;

    f32x4 acc[4][2];
    #pragma unroll
    for (int m = 0; m < 4; ++m)
        #pragma unroll
        for (int nf = 0; nf < 2; ++nf)
            acc[m][nf] = (f32x4){0.f, 0.f, 0.f, 0.f};

    const float* xg = x + (size_t)(b * 384 + gg * 192) * N_SP + bx * 64;
    const ushort* whg = wh + (gg * 384 + by * 128) * 192;
    const ushort* wlg = wl + (gg * 384 + by * 128) * 192;

    for (int kt = 0; kt < 3; ++kt) {
        #pragma unroll
        for (int li = 0; li < 4; ++li) {
            int c = li * 256 + t;
            int row = c >> 3, kb = c & 7;
            int goff = row * 192 + kt * 64 + kb * 8;
            float4 vh = *(const float4*)(whg + goff);
            float4 vl = *(const float4*)(wlg + goff);
            int ch = (row * 8 + (kb ^ (row & 7))) * 8;
            *(float4*)&Ah[ch] = vh;
            *(float4*)&Al[ch] = vl;
        }
        #pragma unroll
        for (int li = 0; li < 2; ++li) {
            int idx = li * 256 + t;
            int kp = idx >> 4;
            int nq = idx & 15;
            int k0 = kp * 2;
            const float* px = xg + (size_t)(kt * 64 + k0) * N_SP + nq * 4;
            float4 v0 = *(const float4*)px;
            float4 v1 = *(const float4*)(px + N_SP);
            ushort h0[4], l0[4], h1[4], l1[4];
            float a0[4] = {v0.x, v0.y, v0.z, v0.w};
            float a1[4] = {v1.x, v1.y, v1.z, v1.w};
            #pragma unroll
            for (int i = 0; i < 4; ++i) { bsplit(a0[i], h0[i], l0[i]); bsplit(a1[i], h1[i], l1[i]); }
            int kb = k0 >> 3, ks = (k0 & 6) >> 1;
            #pragma unroll
            for (int i = 0; i < 4; ++i) {
                int n = nq * 4 + i;
                int chunk = n * 8 + (kb ^ ((n >> 1) & 7));
                ((uint*)Bh)[chunk * 4 + ks] = (uint)h0[i] | ((uint)h1[i] << 16);
                ((uint*)Bl)[chunk * 4 + ks] = (uint)l0[i] | ((uint)l1[i] << 16);
            }
        }
        __syncthreads();
        #pragma unroll
        for (int s = 0; s < 2; ++s) {
            short8 ah[4], al[4], bh[2], bl[2];
            int kb = s * 4 + lg;
            #pragma unroll
            for (int m = 0; m < 4; ++m) {
                int row = wr * 64 + m * 16 + l15;
                int ch = (row * 8 + (kb ^ (row & 7))) * 8;
                ah[m] = *(const short8*)&Ah[ch];
                al[m] = *(const short8*)&Al[ch];
            }
            #pragma unroll
            for (int nf = 0; nf < 2; ++nf) {
                int n = wc * 32 + nf * 16 + l15;
                int ch = (n * 8 + (kb ^ ((n >> 1) & 7))) * 8;
                bh[nf] = *(const short8*)&Bh[ch];
                bl[nf] = *(const short8*)&Bl[ch];
            }
            #pragma unroll
            for (int m = 0; m < 4; ++m)
                #pragma unroll
                for (int nf = 0; nf < 2; ++nf) {
                    acc[m][nf] = __builtin_amdgcn_mfma_f32_16x16x32_bf16(ah[m], bh[nf], acc[m][nf], 0, 0, 0);
                    acc[m][nf] = __builtin_amdgcn_mfma_f32_16x16x32_bf16(ah[m], bl[nf], acc[m][nf], 0, 0, 0);
                    acc[m][nf] = __builtin_amdgcn_mfma_f32_16x16x32_bf16(al[m], bh[nf], acc[m][nf], 0, 0, 0);
                }
        }
        __syncthreads();
    }

    float* scs = (float*)Bh;
    float* shs = scs + 128;
    if (t < 128) {
        int ch = gg * 384 + by * 128 + t;
        float sc = gamma[ch] / sqrtf(var[ch] + BN_EPS);
        scs[t] = sc;
        shs[t] = beta[ch] - mean[ch] * sc;
    }
    __syncthreads();

    size_t obase = ((size_t)(b * 2 + gg) * 384 + by * 128) * N_SP + bx * 64 + wc * 32;
    #pragma unroll
    for (int m = 0; m < 4; ++m)
        #pragma unroll
        for (int nf = 0; nf < 2; ++nf) {
            #pragma unroll
            for (int r = 0; r < 4; ++r) {
                int orow = wr * 64 + m * 16 + lg * 4 + r;
                float v = acc[m][nf][r] * scs[orow] + shs[orow];
                v = v > 0.f ? v + 1.f : __expf(v);
                qk_out[obase + (size_t)orow * N_SP + nf * 16 + l15] = v;
            }
        }
}

// ---------------- K2: kv + ksum via MFMA (unchanged).
__global__ __launch_bounds__(256) void k2_kv_mfma(
    const float* __restrict__ x, const float* __restrict__ qk,
    float* __restrict__ kv_part)
{
    __shared__ __align__(16) ushort Kh[4096], Kl[4096];   // 64 rows x 8 chunks x 8
    __shared__ __align__(16) ushort Vh[5120], Vl[5120];   // 80 rows x 8 chunks x 8

    const int chunk = blockIdx.x;      // 7
    const int h = blockIdx.y, b = blockIdx.z;
    const int t = threadIdx.x;
    const int lane = t & 63, wv = t >> 6;
    const int lg = lane >> 4, l15 = lane & 15;

    const float* kp = qk + (size_t)((b*2+1)*384 + h*64) * N_SP;
    const float* vp = x  + (size_t)(b*384 + h*64) * N_SP;

    #pragma unroll
    for (int li = 0; li < 4; ++li) {
        int idx = li * 256 + t;          // 0..1023
        int row = 64 + (idx >> 6), col = idx & 63;
        int off = (row * 8 + ((col >> 3) ^ (row & 7))) * 8 + (col & 7);
        Vh[off] = (row == 64) ? (ushort)0x3F80 : (ushort)0;
        Vl[off] = 0;
    }

    f32x4 acc[5];
    #pragma unroll
    for (int nf = 0; nf < 5; ++nf) acc[nf] = (f32x4){0.f, 0.f, 0.f, 0.f};

    for (int sub = 0; sub < 7; ++sub) {
        int n0 = chunk * 448 + sub * 64;
        #pragma unroll
        for (int li = 0; li < 4; ++li) {
            int idx = li * 256 + t;      // 0..1023
            int row = idx >> 4, sc = idx & 15;
            int off = (row * 8 + ((sc >> 1) ^ (row & 7))) * 8 + (sc & 1) * 4;
            float4 kf = *(const float4*)&kp[(size_t)row * N_SP + n0 + sc * 4];
            ushort h0,h1,h2,h3,l0,l1,l2,l3;
            bsplit(kf.x,h0,l0); bsplit(kf.y,h1,l1); bsplit(kf.z,h2,l2); bsplit(kf.w,h3,l3);
            ((uint*)&Kh[off])[0] = (uint)h0 | ((uint)h1 << 16);
            ((uint*)&Kh[off])[1] = (uint)h2 | ((uint)h3 << 16);
            ((uint*)&Kl[off])[0] = (uint)l0 | ((uint)l1 << 16);
            ((uint*)&Kl[off])[1] = (uint)l2 | ((uint)l3 << 16);
            float4 vf = *(const float4*)&vp[(size_t)row * N_SP + n0 + sc * 4];
            bsplit(vf.x,h0,l0); bsplit(vf.y,h1,l1); bsplit(vf.z,h2,l2); bsplit(vf.w,h3,l3);
            ((uint*)&Vh[off])[0] = (uint)h0 | ((uint)h1 << 16);
            ((uint*)&Vh[off])[1] = (uint)h2 | ((uint)h3 << 16);
            ((uint*)&Vl[off])[0] = (uint)l0 | ((uint)l1 << 16);
            ((uint*)&Vl[off])[1] = (uint)l2 | ((uint)l3 << 16);
        }
        __syncthreads();
        #pragma unroll
        for (int s = 0; s < 2; ++s) {
            int arow = wv * 16 + l15;
            int akb = (s * 4 + lg) ^ (arow & 7);
            short8 ah = *(const short8*)&Kh[(arow * 8 + akb) * 8];
            short8 al = *(const short8*)&Kl[(arow * 8 + akb) * 8];
            #pragma unroll
            for (int nf = 0; nf < 5; ++nf) {
                int brow = nf * 16 + l15;
                int bkb = (s * 4 + lg) ^ (brow & 7);
                short8 bh = *(const short8*)&Vh[(brow * 8 + bkb) * 8];
                short8 bl = *(const short8*)&Vl[(brow * 8 + bkb) * 8];
                acc[nf] = __builtin_amdgcn_mfma_f32_16x16x32_bf16(ah, bh, acc[nf], 0, 0, 0);
                acc[nf] = __builtin_amdgcn_mfma_f32_16x16x32_bf16(ah, bl, acc[nf], 0, 0, 0);
                acc[nf] = __builtin_amdgcn_mfma_f32_16x16x32_bf16(al, bh, acc[nf], 0, 0, 0);
            }
        }
        __syncthreads();
    }

    size_t base = (size_t)((b*6 + h)*7 + chunk) * 64 * 80;
    #pragma unroll
    for (int nf = 0; nf < 5; ++nf)
        #pragma unroll
        for (int r = 0; r < 4; ++r) {
            int d = wv * 16 + lg * 4 + r;
            kv_part[base + (size_t)d * 80 + nf * 16 + l15] = acc[nf][r];
        }
}

// ---------------- K2b: reduce partials -> kvT bf16 hi/lo planes.
// Output A-matrix for K3: [bh][80 rows][64 d]; rows 0..63 = kv[d][e]/N (e=row),
// row 64 = km[d] = ksum[d]/N, rows 65..79 = 0.
__global__ __launch_bounds__(256) void k2b_reduce(
    const float* __restrict__ kv_part,
    ushort* __restrict__ kvt_h, ushort* __restrict__ kvt_l)
{
    const int bh = blockIdx.x;       // 96
    const int t = threadIdx.x;
    const float inv_n = 1.0f / (float)N_SP;
    const float* base = kv_part + (size_t)bh * 7 * 64 * 80;
    ushort* oh = kvt_h + (size_t)bh * 80 * 64;
    ushort* ol = kvt_l + (size_t)bh * 80 * 64;
    for (int i = t; i < 80 * 64; i += 256) {
        int e = i >> 6, d = i & 63;
        float s = 0.f;
        if (e <= 64) {
            #pragma unroll
            for (int c = 0; c < 7; ++c) s += base[(size_t)(c * 64 + d) * 80 + e];
            s *= inv_n;
        }
        ushort h, l;
        bsplit(s, h, l);
        oh[i] = h; ol[i] = l;
    }
}

// ---------------- K3: attn via MFMA + fused depthwise conv + BN.
// Per (b,h,n-tile64): D[e 0..63 | den row 64][n] = kvT(+km) @ q-tile.
// LDS union: staged Q (16KB) then attn tile [64][68] + den[64].
#define ATT_STRIDE 68
__global__ __launch_bounds__(256) void k3_attn_pe(
    const float* __restrict__ x, const float* __restrict__ qk,
    const ushort* __restrict__ kvt_h, const ushort* __restrict__ kvt_l,
    const float* __restrict__ pw,
    const float* __restrict__ pgamma, const float* __restrict__ pbeta,
    const float* __restrict__ pmean, const float* __restrict__ pvar,
    float* __restrict__ out)
{
    __shared__ __align__(16) float SBF[ATT_STRIDE * 64 + 64];   // 17.7 KB
    ushort* Qh = (ushort*)SBF;          // [4096] (16KB total with Ql, fits)
    ushort* Ql = Qh + 4096;

    const int bx = blockIdx.x;    // 49 n tiles
    const int h = blockIdx.y, b = blockIdx.z;
    const int t = threadIdx.x;
    const int lane = t & 63, wv = t >> 6;
    const int lg = lane >> 4, l15 = lane & 15;
    const int n0 = bx * 64;
    const float* qp = qk + (size_t)((b*2+0)*384 + h*64) * N_SP + n0;

    // ---- stage Q transposed+split into [n][k-chunk] XOR-swizzled LDS
    #pragma unroll
    for (int li = 0; li < 2; ++li) {
        int idx = li * 256 + t;          // 0..511
        int kp2 = idx >> 4;              // 0..31 (d-row pairs)
        int nq = idx & 15;
        int k0 = kp2 * 2;
        const float* px = qp + (size_t)k0 * N_SP + nq * 4;
        float4 v0 = *(const float4*)px;
        float4 v1 = *(const float4*)(px + N_SP);
        ushort h0[4], l0[4], h1[4], l1[4];
        float a0[4] = {v0.x, v0.y, v0.z, v0.w};
        float a1[4] = {v1.x, v1.y, v1.z, v1.w};
        #pragma unroll
        for (int i = 0; i < 4; ++i) { bsplit(a0[i], h0[i], l0[i]); bsplit(a1[i], h1[i], l1[i]); }
        int kb = k0 >> 3, ks = (k0 & 6) >> 1;
        #pragma unroll
        for (int i = 0; i < 4; ++i) {
            int n = nq * 4 + i;
            int chunk = n * 8 + (kb ^ ((n >> 1) & 7));
            ((uint*)Qh)[chunk * 4 + ks] = (uint)h0[i] | ((uint)h1[i] << 16);
            ((uint*)Ql)[chunk * 4 + ks] = (uint)l0[i] | ((uint)l1[i] << 16);
        }
    }
    __syncthreads();

    // ---- B-frags (this wave's n-frag = wv) into regs
    short8 bqh[2], bql[2];
    #pragma unroll
    for (int s = 0; s < 2; ++s) {
        int n = wv * 16 + l15;
        int chunk = n * 8 + ((s * 4 + lg) ^ ((n >> 1) & 7));
        bqh[s] = *(const short8*)&Qh[chunk * 8];
        bql[s] = *(const short8*)&Ql[chunk * 8];
    }
    __syncthreads();   // all waves done with staged Q; LDS reusable

    // ---- MFMA: A-frags from global bf16 planes (L1-hot, 20KB/head)
    const ushort* ahb = kvt_h + (size_t)(b*6 + h) * 80 * 64;
    const ushort* alb = kvt_l + (size_t)(b*6 + h) * 80 * 64;
    f32x4 acc[5];
    #pragma unroll
    for (int m = 0; m < 5; ++m) acc[m] = (f32x4){0.f, 0.f, 0.f, 0.f};
    #pragma unroll
    for (int s = 0; s < 2; ++s) {
        #pragma unroll
        for (int m = 0; m < 5; ++m) {
            int off = (m * 16 + l15) * 64 + (s * 4 + lg) * 8;
            short8 ah = *(const short8*)&ahb[off];
            short8 al = *(const short8*)&alb[off];
            acc[m] = __builtin_amdgcn_mfma_f32_16x16x32_bf16(ah, bqh[s], acc[m], 0, 0, 0);
            acc[m] = __builtin_amdgcn_mfma_f32_16x16x32_bf16(ah, bql[s], acc[m], 0, 0, 0);
            acc[m] = __builtin_amdgcn_mfma_f32_16x16x32_bf16(al, bqh[s], acc[m], 0, 0, 0);
        }
    }

    // ---- write attn tile + den into reused LDS
    {
        int ncol = wv * 16 + l15;
        #pragma unroll
        for (int m = 0; m < 4; ++m)
            #pragma unroll
            for (int r = 0; r < 4; ++r)
                SBF[(m * 16 + lg * 4 + r) * ATT_STRIDE + ncol] = acc[m][r];
        if (lg == 0)
            SBF[ATT_STRIDE * 64 + ncol] = acc[4][0];   // den (A row 64), lg=0 r=0
    }
    __syncthreads();

    // ---- epilogue: tx->4px, ty->4ch; conv identical to prior round
    const int tx = t & 15, ty = t >> 4;
    const int p0 = n0 + tx * 4;
    const int y = p0 / 56, xc = p0 % 56;
    float den[4];
    #pragma unroll
    for (int p = 0; p < 4; ++p) den[p] = SBF[ATT_STRIDE * 64 + tx * 4 + p] + 1e-6f;
    #pragma unroll
    for (int j = 0; j < 4; ++j) {
        int cc = ty * 4 + j;
        int c = h * 64 + cc;
        const float* xp = x + ((size_t)b * 384 + c) * N_SP;
        float s6[3][6];
        #pragma unroll
        for (int dy = 0; dy < 3; ++dy) {
            int yy = y + dy - 1;
            bool yok = (yy >= 0) && (yy < 56);
            float4 mid = make_float4(0.f, 0.f, 0.f, 0.f);
            float lf = 0.f, rt = 0.f;
            if (yok) {
                const float* xr = xp + yy * 56;
                mid = *(const float4*)&xr[xc];
                if (xc > 0)  lf = xr[xc - 1];
                if (xc < 52) rt = xr[xc + 4];
            }
            s6[dy][0] = lf;  s6[dy][1] = mid.x; s6[dy][2] = mid.y;
            s6[dy][3] = mid.z; s6[dy][4] = mid.w; s6[dy][5] = rt;
        }
        float w9[9];
        #pragma unroll
        for (int q = 0; q < 9; ++q) w9[q] = pw[c * 9 + q];
        float sc2 = pgamma[c] / sqrtf(pvar[c] + BN_EPS);
        float sh2 = pbeta[c] - pmean[c] * sc2;
        float4 r;
        float* pr = (float*)&r;
        #pragma unroll
        for (int p = 0; p < 4; ++p) {
            float conv = 0.f;
            #pragma unroll
            for (int dy = 0; dy < 3; ++dy)
                #pragma unroll
                for (int dx = 0; dx < 3; ++dx)
                    conv += w9[dy * 3 + dx] * s6[dy][p + dx];
            float num = SBF[cc * ATT_STRIDE + tx * 4 + p];
            pr[p] = num / den[p] + (conv * sc2 + sh2);
        }
        *(float4*)&out[((size_t)b * 384 + c) * N_SP + p0] = r;
    }
}

extern "C" void kernel_launch(void* const* d_in, const int* in_sizes, int n_in,
                              void* d_out, int out_size, void* d_ws, size_t ws_size,
                              hipStream_t stream)
{
    const float* x        = (const float*)d_in[0];
    const float* qk_w     = (const float*)d_in[1];
    const float* qk_gamma = (const float*)d_in[2];
    const float* qk_beta  = (const float*)d_in[3];
    const float* qk_mean  = (const float*)d_in[4];
    const float* qk_var   = (const float*)d_in[5];
    const float* pe_w     = (const float*)d_in[6];
    const float* pe_gamma = (const float*)d_in[7];
    const float* pe_beta  = (const float*)d_in[8];
    const float* pe_mean  = (const float*)d_in[9];
    const float* pe_var   = (const float*)d_in[10];
    float* out = (float*)d_out;

    float* ws      = (float*)d_ws;
    float* qk      = ws;
    float* kv_part = ws + KVP_OFF;
    ushort* kvt_h  = (ushort*)(ws + KVT_OFF);
    ushort* kvt_l  = kvt_h + 96 * 80 * 64;
    ushort* whp    = (ushort*)(ws + WH_OFF);
    ushort* wlp    = whp + WSPLIT_N;

    hipLaunchKernelGGL(p0_wsplit, dim3((WSPLIT_N + 255)/256), dim3(256), 0, stream,
                       qk_w, whp, wlp);
    dim3 g1(49, 3, 32);
    hipLaunchKernelGGL(k1_qk_mfma, g1, dim3(256), 0, stream,
                       x, whp, wlp, qk_gamma, qk_beta, qk_mean, qk_var, qk);
    dim3 g2(7, 6, 16);
    hipLaunchKernelGGL(k2_kv_mfma, g2, dim3(256), 0, stream, x, qk, kv_part);
    hipLaunchKernelGGL(k2b_reduce, dim3(96), dim3(256), 0, stream,
                       kv_part, kvt_h, kvt_l);
    dim3 g3(49, 6, 16);
    hipLaunchKernelGGL(k3_attn_pe, g3, dim3(256), 0, stream,
                       x, qk, kvt_h, kvt_l, pe_w, pe_gamma, pe_beta, pe_mean, pe_var, out);
}

// Round 6
// 225.369 us; speedup vs baseline: 1.0672x; 1.0672x over previous
//
#include <hip/hip_runtime.h>
#include <math.h>

#define N_SP 3136
#define BN_EPS 1e-5f

typedef __attribute__((ext_vector_type(8))) short short8;
typedef __attribute__((ext_vector_type(4))) float f32x4;

// ws layout (float elements)
#define K_SZ    (16*384*N_SP)            // 19,267,584  (k fp32, group-1 BN+elu output)
#define QF_OFF  (K_SZ)
#define QF_FSZ  (16*6*49*8192/2)         // 19,267,584 floats backing q-frag ushorts
#define KVP_OFF (QF_OFF + QF_FSZ)
#define KVP_SZ  (16*6*7*64*80)           // 3,440,640
#define KVT_OFF (KVP_OFF + KVP_SZ)
#define KVT_FSZ (2*96*80*64/2)           // 491,520
#define WH_OFF  (KVT_OFF + KVT_FSZ)
#define WSPLIT_N (2*384*192)             // 147,456

__device__ __forceinline__ void bsplit(float f, ushort& h, ushort& l) {
    uint u = __float_as_uint(f);
    uint hr = (u + 0x7FFFu + ((u >> 16) & 1u)) >> 16;
    h = (ushort)hr;
    float fh = __uint_as_float(hr << 16);
    float fl = f - fh;
    uint v = __float_as_uint(fl);
    l = (ushort)((v + 0x7FFFu + ((v >> 16) & 1u)) >> 16);
}

// ---------------- P0: split qk_w into bf16 hi/lo planes ([g][o][k], k contiguous)
__global__ __launch_bounds__(256) void p0_wsplit(
    const float* __restrict__ qk_w, ushort* __restrict__ wh, ushort* __restrict__ wl)
{
    int idx = blockIdx.x * 256 + threadIdx.x;
    if (idx >= WSPLIT_N) return;
    ushort h, l;
    bsplit(qk_w[idx], h, l);
    wh[idx] = h;
    wl[idx] = l;
}

// ---------------- K1: qk GEMM via bf16-split MFMA.
// gg=0 (q): epilogue writes MFMA B-fragment bf16 hi/lo layout:
//   qf[(b*6+head)*49+tile][plane(2)][halfchunk(16)][n(64)][4]   (8 KB/plane/tile)
// gg=1 (k): epilogue writes fp32 [b][384][n] as before.
// Grid: (bx=49 n-tiles, bz=32 b*2+g, by=3 o-tiles) -> by outermost in launch for L3 reuse of x.
__global__ __launch_bounds__(256) void k1_qk_mfma(
    const float* __restrict__ x, const ushort* __restrict__ wh, const ushort* __restrict__ wl,
    const float* __restrict__ gamma, const float* __restrict__ beta,
    const float* __restrict__ mean, const float* __restrict__ var,
    float* __restrict__ k_out, ushort* __restrict__ qf)
{
    __shared__ __align__(16) ushort Ah[8192];
    __shared__ __align__(16) ushort Al[8192];
    __shared__ __align__(16) ushort Bh[4096];
    __shared__ __align__(16) ushort Bl[4096];

    const int bx = blockIdx.x;           // 49 n-tiles
    const int bz = blockIdx.y;           // b*2+g
    const int by = blockIdx.z;           // 3 o-tiles (128 each)
    const int b = bz >> 1, gg = bz & 1;
    const int t = threadIdx.x;
    const int lane = t & 63, wv = t >> 6;
    const int wr = wv >> 1, wc = wv & 1;
    const int lg = lane >> 4, l15 = lane & 15;

    f32x4 acc[4][2];
    #pragma unroll
    for (int m = 0; m < 4; ++m)
        #pragma unroll
        for (int nf = 0; nf < 2; ++nf)
            acc[m][nf] = (f32x4){0.f, 0.f, 0.f, 0.f};

    const float* xg = x + (size_t)(b * 384 + gg * 192) * N_SP + bx * 64;
    const ushort* whg = wh + (gg * 384 + by * 128) * 192;
    const ushort* wlg = wl + (gg * 384 + by * 128) * 192;

    for (int kt = 0; kt < 3; ++kt) {
        #pragma unroll
        for (int li = 0; li < 4; ++li) {
            int c = li * 256 + t;
            int row = c >> 3, kb = c & 7;
            int goff = row * 192 + kt * 64 + kb * 8;
            float4 vh = *(const float4*)(whg + goff);
            float4 vl = *(const float4*)(wlg + goff);
            int ch = (row * 8 + (kb ^ (row & 7))) * 8;
            *(float4*)&Ah[ch] = vh;
            *(float4*)&Al[ch] = vl;
        }
        #pragma unroll
        for (int li = 0; li < 2; ++li) {
            int idx = li * 256 + t;
            int kp = idx >> 4;
            int nq = idx & 15;
            int k0 = kp * 2;
            const float* px = xg + (size_t)(kt * 64 + k0) * N_SP + nq * 4;
            float4 v0 = *(const float4*)px;
            float4 v1 = *(const float4*)(px + N_SP);
            ushort h0[4], l0[4], h1[4], l1[4];
            float a0[4] = {v0.x, v0.y, v0.z, v0.w};
            float a1[4] = {v1.x, v1.y, v1.z, v1.w};
            #pragma unroll
            for (int i = 0; i < 4; ++i) { bsplit(a0[i], h0[i], l0[i]); bsplit(a1[i], h1[i], l1[i]); }
            int kb = k0 >> 3, ks = (k0 & 6) >> 1;
            #pragma unroll
            for (int i = 0; i < 4; ++i) {
                int n = nq * 4 + i;
                int chunk = n * 8 + (kb ^ ((n >> 1) & 7));
                ((uint*)Bh)[chunk * 4 + ks] = (uint)h0[i] | ((uint)h1[i] << 16);
                ((uint*)Bl)[chunk * 4 + ks] = (uint)l0[i] | ((uint)l1[i] << 16);
            }
        }
        __syncthreads();
        #pragma unroll
        for (int s = 0; s < 2; ++s) {
            short8 ah[4], al[4], bh[2], bl[2];
            int kb = s * 4 + lg;
            #pragma unroll
            for (int m = 0; m < 4; ++m) {
                int row = wr * 64 + m * 16 + l15;
                int ch = (row * 8 + (kb ^ (row & 7))) * 8;
                ah[m] = *(const short8*)&Ah[ch];
                al[m] = *(const short8*)&Al[ch];
            }
            #pragma unroll
            for (int nf = 0; nf < 2; ++nf) {
                int n = wc * 32 + nf * 16 + l15;
                int ch = (n * 8 + (kb ^ ((n >> 1) & 7))) * 8;
                bh[nf] = *(const short8*)&Bh[ch];
                bl[nf] = *(const short8*)&Bl[ch];
            }
            #pragma unroll
            for (int m = 0; m < 4; ++m)
                #pragma unroll
                for (int nf = 0; nf < 2; ++nf) {
                    acc[m][nf] = __builtin_amdgcn_mfma_f32_16x16x32_bf16(ah[m], bh[nf], acc[m][nf], 0, 0, 0);
                    acc[m][nf] = __builtin_amdgcn_mfma_f32_16x16x32_bf16(ah[m], bl[nf], acc[m][nf], 0, 0, 0);
                    acc[m][nf] = __builtin_amdgcn_mfma_f32_16x16x32_bf16(al[m], bh[nf], acc[m][nf], 0, 0, 0);
                }
        }
        __syncthreads();
    }

    float* scs = (float*)Bh;
    float* shs = scs + 128;
    if (t < 128) {
        int ch = gg * 384 + by * 128 + t;
        float sc = gamma[ch] / sqrtf(var[ch] + BN_EPS);
        scs[t] = sc;
        shs[t] = beta[ch] - mean[ch] * sc;
    }
    __syncthreads();

    if (gg == 0) {
        // q: fragment-layout bf16 hi/lo store (4 consecutive d per lane = one uint2/plane)
        const int head = by * 2 + wr;
        ushort* qbase = qf + ((size_t)(b * 6 + head) * 49 + bx) * 8192;
        #pragma unroll
        for (int m = 0; m < 4; ++m) {
            #pragma unroll
            for (int nf = 0; nf < 2; ++nf) {
                ushort hh[4], ll[4];
                #pragma unroll
                for (int r = 0; r < 4; ++r) {
                    int orow = wr * 64 + m * 16 + lg * 4 + r;
                    float v = acc[m][nf][r] * scs[orow] + shs[orow];
                    v = v > 0.f ? v + 1.f : __expf(v);
                    bsplit(v, hh[r], ll[r]);
                }
                int hc = m * 4 + lg;                 // halfchunk within head (d/4)
                int n = wc * 32 + nf * 16 + l15;
                uint2 uh, ul;
                uh.x = (uint)hh[0] | ((uint)hh[1] << 16);
                uh.y = (uint)hh[2] | ((uint)hh[3] << 16);
                ul.x = (uint)ll[0] | ((uint)ll[1] << 16);
                ul.y = (uint)ll[2] | ((uint)ll[3] << 16);
                *(uint2*)(qbase + (size_t)hc * 256 + n * 4) = uh;
                *(uint2*)(qbase + (size_t)(16 + hc) * 256 + n * 4) = ul;
            }
        }
    } else {
        size_t obase = ((size_t)b * 384 + by * 128) * N_SP + bx * 64 + wc * 32;
        #pragma unroll
        for (int m = 0; m < 4; ++m)
            #pragma unroll
            for (int nf = 0; nf < 2; ++nf) {
                #pragma unroll
                for (int r = 0; r < 4; ++r) {
                    int orow = wr * 64 + m * 16 + lg * 4 + r;
                    float v = acc[m][nf][r] * scs[orow] + shs[orow];
                    v = v > 0.f ? v + 1.f : __expf(v);
                    k_out[obase + (size_t)orow * N_SP + nf * 16 + l15] = v;
                }
            }
    }
}

// ---------------- K2: kv + ksum via MFMA (k now read from k_out buffer).
__global__ __launch_bounds__(256) void k2_kv_mfma(
    const float* __restrict__ x, const float* __restrict__ kbuf,
    float* __restrict__ kv_part)
{
    __shared__ __align__(16) ushort Kh[4096], Kl[4096];   // 64 rows x 8 chunks x 8
    __shared__ __align__(16) ushort Vh[5120], Vl[5120];   // 80 rows x 8 chunks x 8

    const int chunk = blockIdx.x;      // 7
    const int h = blockIdx.y, b = blockIdx.z;
    const int t = threadIdx.x;
    const int lane = t & 63, wv = t >> 6;
    const int lg = lane >> 4, l15 = lane & 15;

    const float* kp = kbuf + (size_t)(b*384 + h*64) * N_SP;
    const float* vp = x   + (size_t)(b*384 + h*64) * N_SP;

    #pragma unroll
    for (int li = 0; li < 4; ++li) {
        int idx = li * 256 + t;
        int row = 64 + (idx >> 6), col = idx & 63;
        int off = (row * 8 + ((col >> 3) ^ (row & 7))) * 8 + (col & 7);
        Vh[off] = (row == 64) ? (ushort)0x3F80 : (ushort)0;
        Vl[off] = 0;
    }

    f32x4 acc[5];
    #pragma unroll
    for (int nf = 0; nf < 5; ++nf) acc[nf] = (f32x4){0.f, 0.f, 0.f, 0.f};

    for (int sub = 0; sub < 7; ++sub) {
        int n0 = chunk * 448 + sub * 64;
        #pragma unroll
        for (int li = 0; li < 4; ++li) {
            int idx = li * 256 + t;
            int row = idx >> 4, sc = idx & 15;
            int off = (row * 8 + ((sc >> 1) ^ (row & 7))) * 8 + (sc & 1) * 4;
            float4 kf = *(const float4*)&kp[(size_t)row * N_SP + n0 + sc * 4];
            ushort h0,h1,h2,h3,l0,l1,l2,l3;
            bsplit(kf.x,h0,l0); bsplit(kf.y,h1,l1); bsplit(kf.z,h2,l2); bsplit(kf.w,h3,l3);
            ((uint*)&Kh[off])[0] = (uint)h0 | ((uint)h1 << 16);
            ((uint*)&Kh[off])[1] = (uint)h2 | ((uint)h3 << 16);
            ((uint*)&Kl[off])[0] = (uint)l0 | ((uint)l1 << 16);
            ((uint*)&Kl[off])[1] = (uint)l2 | ((uint)l3 << 16);
            float4 vf = *(const float4*)&vp[(size_t)row * N_SP + n0 + sc * 4];
            bsplit(vf.x,h0,l0); bsplit(vf.y,h1,l1); bsplit(vf.z,h2,l2); bsplit(vf.w,h3,l3);
            ((uint*)&Vh[off])[0] = (uint)h0 | ((uint)h1 << 16);
            ((uint*)&Vh[off])[1] = (uint)h2 | ((uint)h3 << 16);
            ((uint*)&Vl[off])[0] = (uint)l0 | ((uint)l1 << 16);
            ((uint*)&Vl[off])[1] = (uint)l2 | ((uint)l3 << 16);
        }
        __syncthreads();
        #pragma unroll
        for (int s = 0; s < 2; ++s) {
            int arow = wv * 16 + l15;
            int akb = (s * 4 + lg) ^ (arow & 7);
            short8 ah = *(const short8*)&Kh[(arow * 8 + akb) * 8];
            short8 al = *(const short8*)&Kl[(arow * 8 + akb) * 8];
            #pragma unroll
            for (int nf = 0; nf < 5; ++nf) {
                int brow = nf * 16 + l15;
                int bkb = (s * 4 + lg) ^ (brow & 7);
                short8 bh = *(const short8*)&Vh[(brow * 8 + bkb) * 8];
                short8 bl = *(const short8*)&Vl[(brow * 8 + bkb) * 8];
                acc[nf] = __builtin_amdgcn_mfma_f32_16x16x32_bf16(ah, bh, acc[nf], 0, 0, 0);
                acc[nf] = __builtin_amdgcn_mfma_f32_16x16x32_bf16(ah, bl, acc[nf], 0, 0, 0);
                acc[nf] = __builtin_amdgcn_mfma_f32_16x16x32_bf16(al, bh, acc[nf], 0, 0, 0);
            }
        }
        __syncthreads();
    }

    size_t base = (size_t)((b*6 + h)*7 + chunk) * 64 * 80;
    #pragma unroll
    for (int nf = 0; nf < 5; ++nf)
        #pragma unroll
        for (int r = 0; r < 4; ++r) {
            int d = wv * 16 + lg * 4 + r;
            kv_part[base + (size_t)d * 80 + nf * 16 + l15] = acc[nf][r];
        }
}

// ---------------- K2b: reduce partials -> kvT bf16 hi/lo planes [e(80)][d(64)].
// Coalesced linear reads (kv_part is [c][d][80] = linear 5120/c), register accumulate.
__global__ __launch_bounds__(256) void k2b_reduce(
    const float* __restrict__ kv_part,
    ushort* __restrict__ kvt_h, ushort* __restrict__ kvt_l)
{
    const int bh = blockIdx.x;       // 96
    const int t = threadIdx.x;
    const float inv_n = 1.0f / (float)N_SP;
    const float* base = kv_part + (size_t)bh * 7 * 5120;
    ushort* oh = kvt_h + (size_t)bh * 5120;
    ushort* ol = kvt_l + (size_t)bh * 5120;
    float s[20];
    #pragma unroll
    for (int j = 0; j < 20; ++j) s[j] = 0.f;
    for (int c = 0; c < 7; ++c) {
        #pragma unroll
        for (int j = 0; j < 20; ++j) s[j] += base[c * 5120 + j * 256 + t];
    }
    #pragma unroll
    for (int j = 0; j < 20; ++j) {
        int i = j * 256 + t;
        int d = i / 80, e = i % 80;       // kv_part rows 65..79 are zero by construction
        ushort h, l;
        bsplit(s[j] * inv_n, h, l);
        oh[e * 64 + d] = h;
        ol[e * 64 + d] = l;
    }
}

// ---------------- K3: attn via MFMA (frag-direct loads) + fused depthwise conv + BN.
#define ATT_STRIDE 68
__global__ __launch_bounds__(256) void k3_attn_pe(
    const float* __restrict__ x, const ushort* __restrict__ qf,
    const ushort* __restrict__ kvt_h, const ushort* __restrict__ kvt_l,
    const float* __restrict__ pw,
    const float* __restrict__ pgamma, const float* __restrict__ pbeta,
    const float* __restrict__ pmean, const float* __restrict__ pvar,
    float* __restrict__ out)
{
    __shared__ __align__(16) float SBF[ATT_STRIDE * 64 + 64];   // 17.7 KB

    const int bx = blockIdx.x;    // 49 n tiles
    const int h = blockIdx.y, b = blockIdx.z;
    const int t = threadIdx.x;
    const int lane = t & 63, wv = t >> 6;
    const int lg = lane >> 4, l15 = lane & 15;
    const int n0 = bx * 64;

    // ---- B-frags direct from global q-frag layout (coalesced uint2 loads)
    const ushort* qtile = qf + ((size_t)(b * 6 + h) * 49 + bx) * 8192;
    short8 bqh[2], bql[2];
    #pragma unroll
    for (int s = 0; s < 2; ++s) {
        int hc = (s * 4 + lg) * 2;
        const ushort* ph = qtile + hc * 256 + (wv * 16 + l15) * 4;
        uint2 a0 = *(const uint2*)ph;
        uint2 a1 = *(const uint2*)(ph + 256);
        uint* bh = (uint*)&bqh[s];
        bh[0] = a0.x; bh[1] = a0.y; bh[2] = a1.x; bh[3] = a1.y;
        const ushort* pl = ph + 16 * 256;
        uint2 c0 = *(const uint2*)pl;
        uint2 c1 = *(const uint2*)(pl + 256);
        uint* blp = (uint*)&bql[s];
        blp[0] = c0.x; blp[1] = c0.y; blp[2] = c1.x; blp[3] = c1.y;
    }

    // ---- MFMA: A-frags from global bf16 planes (L2-hot, 20KB/head)
    const ushort* ahb = kvt_h + (size_t)(b * 6 + h) * 5120;
    const ushort* alb = kvt_l + (size_t)(b * 6 + h) * 5120;
    f32x4 acc[5];
    #pragma unroll
    for (int m = 0; m < 5; ++m) acc[m] = (f32x4){0.f, 0.f, 0.f, 0.f};
    #pragma unroll
    for (int s = 0; s < 2; ++s) {
        #pragma unroll
        for (int m = 0; m < 5; ++m) {
            int off = (m * 16 + l15) * 64 + (s * 4 + lg) * 8;
            short8 ah = *(const short8*)&ahb[off];
            short8 al = *(const short8*)&alb[off];
            acc[m] = __builtin_amdgcn_mfma_f32_16x16x32_bf16(ah, bqh[s], acc[m], 0, 0, 0);
            acc[m] = __builtin_amdgcn_mfma_f32_16x16x32_bf16(ah, bql[s], acc[m], 0, 0, 0);
            acc[m] = __builtin_amdgcn_mfma_f32_16x16x32_bf16(al, bqh[s], acc[m], 0, 0, 0);
        }
    }

    // ---- write attn tile + den into LDS
    {
        int ncol = wv * 16 + l15;
        #pragma unroll
        for (int m = 0; m < 4; ++m)
            #pragma unroll
            for (int r = 0; r < 4; ++r)
                SBF[(m * 16 + lg * 4 + r) * ATT_STRIDE + ncol] = acc[m][r];
        if (lg == 0)
            SBF[ATT_STRIDE * 64 + ncol] = acc[4][0];
    }
    __syncthreads();

    // ---- epilogue: tx->4px, ty->4ch; fused conv + BN
    const int tx = t & 15, ty = t >> 4;
    const int p0 = n0 + tx * 4;
    const int y = p0 / 56, xc = p0 % 56;
    float den[4];
    #pragma unroll
    for (int p = 0; p < 4; ++p) den[p] = SBF[ATT_STRIDE * 64 + tx * 4 + p] + 1e-6f;
    #pragma unroll
    for (int j = 0; j < 4; ++j) {
        int cc = ty * 4 + j;
        int c = h * 64 + cc;
        const float* xp = x + ((size_t)b * 384 + c) * N_SP;
        float s6[3][6];
        #pragma unroll
        for (int dy = 0; dy < 3; ++dy) {
            int yy = y + dy - 1;
            bool yok = (yy >= 0) && (yy < 56);
            float4 mid = make_float4(0.f, 0.f, 0.f, 0.f);
            float lf = 0.f, rt = 0.f;
            if (yok) {
                const float* xr = xp + yy * 56;
                mid = *(const float4*)&xr[xc];
                if (xc > 0)  lf = xr[xc - 1];
                if (xc < 52) rt = xr[xc + 4];
            }
            s6[dy][0] = lf;  s6[dy][1] = mid.x; s6[dy][2] = mid.y;
            s6[dy][3] = mid.z; s6[dy][4] = mid.w; s6[dy][5] = rt;
        }
        float w9[9];
        #pragma unroll
        for (int q = 0; q < 9; ++q) w9[q] = pw[c * 9 + q];
        float sc2 = pgamma[c] / sqrtf(pvar[c] + BN_EPS);
        float sh2 = pbeta[c] - pmean[c] * sc2;
        float4 r;
        float* pr = (float*)&r;
        #pragma unroll
        for (int p = 0; p < 4; ++p) {
            float conv = 0.f;
            #pragma unroll
            for (int dy = 0; dy < 3; ++dy)
                #pragma unroll
                for (int dx = 0; dx < 3; ++dx)
                    conv += w9[dy * 3 + dx] * s6[dy][p + dx];
            float num = SBF[cc * ATT_STRIDE + tx * 4 + p];
            pr[p] = num / den[p] + (conv * sc2 + sh2);
        }
        *(float4*)&out[((size_t)b * 384 + c) * N_SP + p0] = r;
    }
}

extern "C" void kernel_launch(void* const* d_in, const int* in_sizes, int n_in,
                              void* d_out, int out_size, void* d_ws, size_t ws_size,
                              hipStream_t stream)
{
    const float* x        = (const float*)d_in[0];
    const float* qk_w     = (const float*)d_in[1];
    const float* qk_gamma = (const float*)d_in[2];
    const float* qk_beta  = (const float*)d_in[3];
    const float* qk_mean  = (const float*)d_in[4];
    const float* qk_var   = (const float*)d_in[5];
    const float* pe_w     = (const float*)d_in[6];
    const float* pe_gamma = (const float*)d_in[7];
    const float* pe_beta  = (const float*)d_in[8];
    const float* pe_mean  = (const float*)d_in[9];
    const float* pe_var   = (const float*)d_in[10];
    float* out = (float*)d_out;

    float* ws      = (float*)d_ws;
    float* kbuf    = ws;
    ushort* qf     = (ushort*)(ws + QF_OFF);
    float* kv_part = ws + KVP_OFF;
    ushort* kvt_h  = (ushort*)(ws + KVT_OFF);
    ushort* kvt_l  = kvt_h + 96 * 5120;
    ushort* whp    = (ushort*)(ws + WH_OFF);
    ushort* wlp    = whp + WSPLIT_N;

    hipLaunchKernelGGL(p0_wsplit, dim3((WSPLIT_N + 255)/256), dim3(256), 0, stream,
                       qk_w, whp, wlp);
    dim3 g1(49, 32, 3);   // (bx, bz, by): by outermost -> x L3 reuse across o-tiles
    hipLaunchKernelGGL(k1_qk_mfma, g1, dim3(256), 0, stream,
                       x, whp, wlp, qk_gamma, qk_beta, qk_mean, qk_var, kbuf, qf);
    dim3 g2(7, 6, 16);
    hipLaunchKernelGGL(k2_kv_mfma, g2, dim3(256), 0, stream, x, kbuf, kv_part);
    hipLaunchKernelGGL(k2b_reduce, dim3(96), dim3(256), 0, stream,
                       kv_part, kvt_h, kvt_l);
    dim3 g3(49, 6, 16);
    hipLaunchKernelGGL(k3_attn_pe, g3, dim3(256), 0, stream,
                       x, qf, kvt_h, kvt_l, pe_w, pe_gamma, pe_beta, pe_mean, pe_var, out);
}

// Round 7
// 222.222 us; speedup vs baseline: 1.0824x; 1.0142x over previous
//
#include <hip/hip_runtime.h>
#include <math.h>

#define N_SP 3136
#define BN_EPS 1e-5f

typedef __attribute__((ext_vector_type(8))) short short8;
typedef __attribute__((ext_vector_type(4))) float f32x4;

// ws layout (float elements)
#define K_SZ    (16*384*N_SP)            // 19,267,584  (k fp32, group-1 BN+elu output)
#define QF_OFF  (K_SZ)
#define QF_FSZ  (16*6*49*8192/2)         // 19,267,584 floats backing q-frag ushorts
#define KVP_OFF (QF_OFF + QF_FSZ)
#define KVP_SZ  (16*6*7*64*80)           // 3,440,640
#define KVT_OFF (KVP_OFF + KVP_SZ)
#define KVT_FSZ (2*96*80*64/2)           // 491,520
#define WH_OFF  (KVT_OFF + KVT_FSZ)
#define WSPLIT_N (2*384*192)             // 147,456

__device__ __forceinline__ void bsplit(float f, ushort& h, ushort& l) {
    uint u = __float_as_uint(f);
    uint hr = (u + 0x7FFFu + ((u >> 16) & 1u)) >> 16;
    h = (ushort)hr;
    float fh = __uint_as_float(hr << 16);
    float fl = f - fh;
    uint v = __float_as_uint(fl);
    l = (ushort)((v + 0x7FFFu + ((v >> 16) & 1u)) >> 16);
}

// ---------------- P0: split qk_w into bf16 hi/lo planes ([g][o][k], k contiguous)
__global__ __launch_bounds__(256) void p0_wsplit(
    const float* __restrict__ qk_w, ushort* __restrict__ wh, ushort* __restrict__ wl)
{
    int idx = blockIdx.x * 256 + threadIdx.x;
    if (idx >= WSPLIT_N) return;
    ushort h, l;
    bsplit(qk_w[idx], h, l);
    wh[idx] = h;
    wl[idx] = l;
}

// ---------------- K1: qk GEMM via bf16-split MFMA (unchanged from r5).
__global__ __launch_bounds__(256) void k1_qk_mfma(
    const float* __restrict__ x, const ushort* __restrict__ wh, const ushort* __restrict__ wl,
    const float* __restrict__ gamma, const float* __restrict__ beta,
    const float* __restrict__ mean, const float* __restrict__ var,
    float* __restrict__ k_out, ushort* __restrict__ qf)
{
    __shared__ __align__(16) ushort Ah[8192];
    __shared__ __align__(16) ushort Al[8192];
    __shared__ __align__(16) ushort Bh[4096];
    __shared__ __align__(16) ushort Bl[4096];

    const int bx = blockIdx.x;           // 49 n-tiles
    const int bz = blockIdx.y;           // b*2+g
    const int by = blockIdx.z;           // 3 o-tiles (128 each)
    const int b = bz >> 1, gg = bz & 1;
    const int t = threadIdx.x;
    const int lane = t & 63, wv = t >> 6;
    const int wr = wv >> 1, wc = wv & 1;
    const int lg = lane >> 4, l15 = lane & 15;

    f32x4 acc[4][2];
    #pragma unroll
    for (int m = 0; m < 4; ++m)
        #pragma unroll
        for (int nf = 0; nf < 2; ++nf)
            acc[m][nf] = (f32x4){0.f, 0.f, 0.f, 0.f};

    const float* xg = x + (size_t)(b * 384 + gg * 192) * N_SP + bx * 64;
    const ushort* whg = wh + (gg * 384 + by * 128) * 192;
    const ushort* wlg = wl + (gg * 384 + by * 128) * 192;

    for (int kt = 0; kt < 3; ++kt) {
        #pragma unroll
        for (int li = 0; li < 4; ++li) {
            int c = li * 256 + t;
            int row = c >> 3, kb = c & 7;
            int goff = row * 192 + kt * 64 + kb * 8;
            float4 vh = *(const float4*)(whg + goff);
            float4 vl = *(const float4*)(wlg + goff);
            int ch = (row * 8 + (kb ^ (row & 7))) * 8;
            *(float4*)&Ah[ch] = vh;
            *(float4*)&Al[ch] = vl;
        }
        #pragma unroll
        for (int li = 0; li < 2; ++li) {
            int idx = li * 256 + t;
            int kp = idx >> 4;
            int nq = idx & 15;
            int k0 = kp * 2;
            const float* px = xg + (size_t)(kt * 64 + k0) * N_SP + nq * 4;
            float4 v0 = *(const float4*)px;
            float4 v1 = *(const float4*)(px + N_SP);
            ushort h0[4], l0[4], h1[4], l1[4];
            float a0[4] = {v0.x, v0.y, v0.z, v0.w};
            float a1[4] = {v1.x, v1.y, v1.z, v1.w};
            #pragma unroll
            for (int i = 0; i < 4; ++i) { bsplit(a0[i], h0[i], l0[i]); bsplit(a1[i], h1[i], l1[i]); }
            int kb = k0 >> 3, ks = (k0 & 6) >> 1;
            #pragma unroll
            for (int i = 0; i < 4; ++i) {
                int n = nq * 4 + i;
                int chunk = n * 8 + (kb ^ ((n >> 1) & 7));
                ((uint*)Bh)[chunk * 4 + ks] = (uint)h0[i] | ((uint)h1[i] << 16);
                ((uint*)Bl)[chunk * 4 + ks] = (uint)l0[i] | ((uint)l1[i] << 16);
            }
        }
        __syncthreads();
        #pragma unroll
        for (int s = 0; s < 2; ++s) {
            short8 ah[4], al[4], bh[2], bl[2];
            int kb = s * 4 + lg;
            #pragma unroll
            for (int m = 0; m < 4; ++m) {
                int row = wr * 64 + m * 16 + l15;
                int ch = (row * 8 + (kb ^ (row & 7))) * 8;
                ah[m] = *(const short8*)&Ah[ch];
                al[m] = *(const short8*)&Al[ch];
            }
            #pragma unroll
            for (int nf = 0; nf < 2; ++nf) {
                int n = wc * 32 + nf * 16 + l15;
                int ch = (n * 8 + (kb ^ ((n >> 1) & 7))) * 8;
                bh[nf] = *(const short8*)&Bh[ch];
                bl[nf] = *(const short8*)&Bl[ch];
            }
            #pragma unroll
            for (int m = 0; m < 4; ++m)
                #pragma unroll
                for (int nf = 0; nf < 2; ++nf) {
                    acc[m][nf] = __builtin_amdgcn_mfma_f32_16x16x32_bf16(ah[m], bh[nf], acc[m][nf], 0, 0, 0);
                    acc[m][nf] = __builtin_amdgcn_mfma_f32_16x16x32_bf16(ah[m], bl[nf], acc[m][nf], 0, 0, 0);
                    acc[m][nf] = __builtin_amdgcn_mfma_f32_16x16x32_bf16(al[m], bh[nf], acc[m][nf], 0, 0, 0);
                }
        }
        __syncthreads();
    }

    float* scs = (float*)Bh;
    float* shs = scs + 128;
    if (t < 128) {
        int ch = gg * 384 + by * 128 + t;
        float sc = gamma[ch] / sqrtf(var[ch] + BN_EPS);
        scs[t] = sc;
        shs[t] = beta[ch] - mean[ch] * sc;
    }
    __syncthreads();

    if (gg == 0) {
        const int head = by * 2 + wr;
        ushort* qbase = qf + ((size_t)(b * 6 + head) * 49 + bx) * 8192;
        #pragma unroll
        for (int m = 0; m < 4; ++m) {
            #pragma unroll
            for (int nf = 0; nf < 2; ++nf) {
                ushort hh[4], ll[4];
                #pragma unroll
                for (int r = 0; r < 4; ++r) {
                    int orow = wr * 64 + m * 16 + lg * 4 + r;
                    float v = acc[m][nf][r] * scs[orow] + shs[orow];
                    v = v > 0.f ? v + 1.f : __expf(v);
                    bsplit(v, hh[r], ll[r]);
                }
                int hc = m * 4 + lg;
                int n = wc * 32 + nf * 16 + l15;
                uint2 uh, ul;
                uh.x = (uint)hh[0] | ((uint)hh[1] << 16);
                uh.y = (uint)hh[2] | ((uint)hh[3] << 16);
                ul.x = (uint)ll[0] | ((uint)ll[1] << 16);
                ul.y = (uint)ll[2] | ((uint)ll[3] << 16);
                *(uint2*)(qbase + (size_t)hc * 256 + n * 4) = uh;
                *(uint2*)(qbase + (size_t)(16 + hc) * 256 + n * 4) = ul;
            }
        }
    } else {
        size_t obase = ((size_t)b * 384 + by * 128) * N_SP + bx * 64 + wc * 32;
        #pragma unroll
        for (int m = 0; m < 4; ++m)
            #pragma unroll
            for (int nf = 0; nf < 2; ++nf) {
                #pragma unroll
                for (int r = 0; r < 4; ++r) {
                    int orow = wr * 64 + m * 16 + lg * 4 + r;
                    float v = acc[m][nf][r] * scs[orow] + shs[orow];
                    v = v > 0.f ? v + 1.f : __expf(v);
                    k_out[obase + (size_t)orow * N_SP + nf * 16 + l15] = v;
                }
            }
    }
}

// ---------------- K2: kv + ksum via MFMA (unchanged).
__global__ __launch_bounds__(256) void k2_kv_mfma(
    const float* __restrict__ x, const float* __restrict__ kbuf,
    float* __restrict__ kv_part)
{
    __shared__ __align__(16) ushort Kh[4096], Kl[4096];
    __shared__ __align__(16) ushort Vh[5120], Vl[5120];

    const int chunk = blockIdx.x;      // 7
    const int h = blockIdx.y, b = blockIdx.z;
    const int t = threadIdx.x;
    const int lane = t & 63, wv = t >> 6;
    const int lg = lane >> 4, l15 = lane & 15;

    const float* kp = kbuf + (size_t)(b*384 + h*64) * N_SP;
    const float* vp = x   + (size_t)(b*384 + h*64) * N_SP;

    #pragma unroll
    for (int li = 0; li < 4; ++li) {
        int idx = li * 256 + t;
        int row = 64 + (idx >> 6), col = idx & 63;
        int off = (row * 8 + ((col >> 3) ^ (row & 7))) * 8 + (col & 7);
        Vh[off] = (row == 64) ? (ushort)0x3F80 : (ushort)0;
        Vl[off] = 0;
    }

    f32x4 acc[5];
    #pragma unroll
    for (int nf = 0; nf < 5; ++nf) acc[nf] = (f32x4){0.f, 0.f, 0.f, 0.f};

    for (int sub = 0; sub < 7; ++sub) {
        int n0 = chunk * 448 + sub * 64;
        #pragma unroll
        for (int li = 0; li < 4; ++li) {
            int idx = li * 256 + t;
            int row = idx >> 4, sc = idx & 15;
            int off = (row * 8 + ((sc >> 1) ^ (row & 7))) * 8 + (sc & 1) * 4;
            float4 kf = *(const float4*)&kp[(size_t)row * N_SP + n0 + sc * 4];
            ushort h0,h1,h2,h3,l0,l1,l2,l3;
            bsplit(kf.x,h0,l0); bsplit(kf.y,h1,l1); bsplit(kf.z,h2,l2); bsplit(kf.w,h3,l3);
            ((uint*)&Kh[off])[0] = (uint)h0 | ((uint)h1 << 16);
            ((uint*)&Kh[off])[1] = (uint)h2 | ((uint)h3 << 16);
            ((uint*)&Kl[off])[0] = (uint)l0 | ((uint)l1 << 16);
            ((uint*)&Kl[off])[1] = (uint)l2 | ((uint)l3 << 16);
            float4 vf = *(const float4*)&vp[(size_t)row * N_SP + n0 + sc * 4];
            bsplit(vf.x,h0,l0); bsplit(vf.y,h1,l1); bsplit(vf.z,h2,l2); bsplit(vf.w,h3,l3);
            ((uint*)&Vh[off])[0] = (uint)h0 | ((uint)h1 << 16);
            ((uint*)&Vh[off])[1] = (uint)h2 | ((uint)h3 << 16);
            ((uint*)&Vl[off])[0] = (uint)l0 | ((uint)l1 << 16);
            ((uint*)&Vl[off])[1] = (uint)l2 | ((uint)l3 << 16);
        }
        __syncthreads();
        #pragma unroll
        for (int s = 0; s < 2; ++s) {
            int arow = wv * 16 + l15;
            int akb = (s * 4 + lg) ^ (arow & 7);
            short8 ah = *(const short8*)&Kh[(arow * 8 + akb) * 8];
            short8 al = *(const short8*)&Kl[(arow * 8 + akb) * 8];
            #pragma unroll
            for (int nf = 0; nf < 5; ++nf) {
                int brow = nf * 16 + l15;
                int bkb = (s * 4 + lg) ^ (brow & 7);
                short8 bh = *(const short8*)&Vh[(brow * 8 + bkb) * 8];
                short8 bl = *(const short8*)&Vl[(brow * 8 + bkb) * 8];
                acc[nf] = __builtin_amdgcn_mfma_f32_16x16x32_bf16(ah, bh, acc[nf], 0, 0, 0);
                acc[nf] = __builtin_amdgcn_mfma_f32_16x16x32_bf16(ah, bl, acc[nf], 0, 0, 0);
                acc[nf] = __builtin_amdgcn_mfma_f32_16x16x32_bf16(al, bh, acc[nf], 0, 0, 0);
            }
        }
        __syncthreads();
    }

    size_t base = (size_t)((b*6 + h)*7 + chunk) * 64 * 80;
    #pragma unroll
    for (int nf = 0; nf < 5; ++nf)
        #pragma unroll
        for (int r = 0; r < 4; ++r) {
            int d = wv * 16 + lg * 4 + r;
            kv_part[base + (size_t)d * 80 + nf * 16 + l15] = acc[nf][r];
        }
}

// ---------------- K2b: reduce partials -> kvT bf16 hi/lo planes [e(80)][d(64)] (unchanged).
__global__ __launch_bounds__(256) void k2b_reduce(
    const float* __restrict__ kv_part,
    ushort* __restrict__ kvt_h, ushort* __restrict__ kvt_l)
{
    const int bh = blockIdx.x;       // 96
    const int t = threadIdx.x;
    const float inv_n = 1.0f / (float)N_SP;
    const float* base = kv_part + (size_t)bh * 7 * 5120;
    ushort* oh = kvt_h + (size_t)bh * 5120;
    ushort* ol = kvt_l + (size_t)bh * 5120;
    float s[20];
    #pragma unroll
    for (int j = 0; j < 20; ++j) s[j] = 0.f;
    for (int c = 0; c < 7; ++c) {
        #pragma unroll
        for (int j = 0; j < 20; ++j) s[j] += base[c * 5120 + j * 256 + t];
    }
    #pragma unroll
    for (int j = 0; j < 20; ++j) {
        int i = j * 256 + t;
        int d = i / 80, e = i % 80;
        ushort h, l;
        bsplit(s[j] * inv_n, h, l);
        oh[e * 64 + d] = h;
        ol[e * 64 + d] = l;
    }
}

__device__ __forceinline__ void load_qfrag(const ushort* qtile, int wv, int lg, int l15,
                                           short8* qh, short8* ql)
{
    #pragma unroll
    for (int s = 0; s < 2; ++s) {
        int hc = (s * 4 + lg) * 2;
        const ushort* ph = qtile + hc * 256 + (wv * 16 + l15) * 4;
        uint2 a0 = *(const uint2*)ph;
        uint2 a1 = *(const uint2*)(ph + 256);
        uint* bh = (uint*)&qh[s];
        bh[0] = a0.x; bh[1] = a0.y; bh[2] = a1.x; bh[3] = a1.y;
        const ushort* pl = ph + 16 * 256;
        uint2 c0 = *(const uint2*)pl;
        uint2 c1 = *(const uint2*)(pl + 256);
        uint* bl = (uint*)&ql[s];
        bl[0] = c0.x; bl[1] = c0.y; bl[2] = c1.x; bl[3] = c1.y;
    }
}

// ---------------- K3: per-(b,h) 7-tile strip; kvt in LDS (staged once), q prefetched.
#define ATT_STRIDE 68
__global__ __launch_bounds__(256) void k3_attn_pe(
    const float* __restrict__ x, const ushort* __restrict__ qf,
    const ushort* __restrict__ kvt_h, const ushort* __restrict__ kvt_l,
    const float* __restrict__ pw,
    const float* __restrict__ pgamma, const float* __restrict__ pbeta,
    const float* __restrict__ pmean, const float* __restrict__ pvar,
    float* __restrict__ out)
{
    __shared__ __align__(16) ushort KVH[5120], KVL[5120];           // 20.5 KB
    __shared__ __align__(16) float SBF[ATT_STRIDE * 64 + 64];       // 17.3 KB

    const int h = blockIdx.y, b = blockIdx.z;
    const int t = threadIdx.x;
    const int lane = t & 63, wv = t >> 6;
    const int lg = lane >> 4, l15 = lane & 15;

    // ---- stage kvt planes into LDS (chunk-XOR swizzle: conflict-free frag reads)
    const ushort* gh = kvt_h + (size_t)(b * 6 + h) * 5120;
    const ushort* gl = kvt_l + (size_t)(b * 6 + h) * 5120;
    for (int c = t; c < 640; c += 256) {
        int e = c >> 3, i = c & 7;
        int dst = (e * 8 + (i ^ (e & 7))) * 8;
        *(float4*)&KVH[dst] = *(const float4*)&gh[c * 8];
        *(float4*)&KVL[dst] = *(const float4*)&gl[c * 8];
    }

    const ushort* qstrip = qf + ((size_t)(b * 6 + h) * 49 + blockIdx.x * 7) * 8192;
    short8 qch[2], qcl[2], qnh[2], qnl[2];
    load_qfrag(qstrip, wv, lg, l15, qch, qcl);
    __syncthreads();

    const int tx = t & 15, ty = t >> 4;
    float sc2[4], sh2[4], w9[4][9];
    #pragma unroll
    for (int j = 0; j < 4; ++j) {
        int c = h * 64 + ty * 4 + j;
        sc2[j] = pgamma[c] / sqrtf(pvar[c] + BN_EPS);
        sh2[j] = pbeta[c] - pmean[c] * sc2[j];
        #pragma unroll
        for (int q = 0; q < 9; ++q) w9[j][q] = pw[c * 9 + q];
    }

    for (int tt = 0; tt < 7; ++tt) {
        const int bx = blockIdx.x * 7 + tt;
        const int n0 = bx * 64;

        // prefetch next tile's q frags (stays in flight across barriers)
        if (tt < 6)
            load_qfrag(qstrip + (size_t)(tt + 1) * 8192, wv, lg, l15, qnh, qnl);

        // ---- MFMA: A-frags from LDS, B-frags = current q regs
        f32x4 acc[5];
        #pragma unroll
        for (int m = 0; m < 5; ++m) acc[m] = (f32x4){0.f, 0.f, 0.f, 0.f};
        #pragma unroll
        for (int s = 0; s < 2; ++s) {
            #pragma unroll
            for (int m = 0; m < 5; ++m) {
                int off = ((m * 16 + l15) * 8 + ((s * 4 + lg) ^ (l15 & 7))) * 8;
                short8 ah = *(const short8*)&KVH[off];
                short8 al = *(const short8*)&KVL[off];
                acc[m] = __builtin_amdgcn_mfma_f32_16x16x32_bf16(ah, qch[s], acc[m], 0, 0, 0);
                acc[m] = __builtin_amdgcn_mfma_f32_16x16x32_bf16(ah, qcl[s], acc[m], 0, 0, 0);
                acc[m] = __builtin_amdgcn_mfma_f32_16x16x32_bf16(al, qch[s], acc[m], 0, 0, 0);
            }
        }

        // ---- write attn tile + den into LDS
        {
            int ncol = wv * 16 + l15;
            #pragma unroll
            for (int m = 0; m < 4; ++m)
                #pragma unroll
                for (int r = 0; r < 4; ++r)
                    SBF[(m * 16 + lg * 4 + r) * ATT_STRIDE + ncol] = acc[m][r];
            if (lg == 0)
                SBF[ATT_STRIDE * 64 + ncol] = acc[4][0];
        }
        __syncthreads();

        // ---- epilogue: tx->4px, ty->4ch; fused conv + BN
        const int p0 = n0 + tx * 4;
        const int y = p0 / 56, xc = p0 % 56;
        float den[4];
        #pragma unroll
        for (int p = 0; p < 4; ++p) den[p] = SBF[ATT_STRIDE * 64 + tx * 4 + p] + 1e-6f;
        #pragma unroll
        for (int j = 0; j < 4; ++j) {
            int cc = ty * 4 + j;
            int c = h * 64 + cc;
            const float* xp = x + ((size_t)b * 384 + c) * N_SP;
            float s6[3][6];
            #pragma unroll
            for (int dy = 0; dy < 3; ++dy) {
                int yy = y + dy - 1;
                bool yok = (yy >= 0) && (yy < 56);
                float4 mid = make_float4(0.f, 0.f, 0.f, 0.f);
                float lf = 0.f, rt = 0.f;
                if (yok) {
                    const float* xr = xp + yy * 56;
                    mid = *(const float4*)&xr[xc];
                    if (xc > 0)  lf = xr[xc - 1];
                    if (xc < 52) rt = xr[xc + 4];
                }
                s6[dy][0] = lf;  s6[dy][1] = mid.x; s6[dy][2] = mid.y;
                s6[dy][3] = mid.z; s6[dy][4] = mid.w; s6[dy][5] = rt;
            }
            float4 r;
            float* pr = (float*)&r;
            #pragma unroll
            for (int p = 0; p < 4; ++p) {
                float conv = 0.f;
                #pragma unroll
                for (int dy = 0; dy < 3; ++dy)
                    #pragma unroll
                    for (int dx = 0; dx < 3; ++dx)
                        conv += w9[j][dy * 3 + dx] * s6[dy][p + dx];
                float num = SBF[cc * ATT_STRIDE + tx * 4 + p];
                pr[p] = num / den[p] + (conv * sc2[j] + sh2[j]);
            }
            *(float4*)&out[((size_t)b * 384 + c) * N_SP + p0] = r;
        }

        if (tt < 6) {
            __syncthreads();   // protect SBF before next iteration overwrites it
            #pragma unroll
            for (int s = 0; s < 2; ++s) { qch[s] = qnh[s]; qcl[s] = qnl[s]; }
        }
    }
}

extern "C" void kernel_launch(void* const* d_in, const int* in_sizes, int n_in,
                              void* d_out, int out_size, void* d_ws, size_t ws_size,
                              hipStream_t stream)
{
    const float* x        = (const float*)d_in[0];
    const float* qk_w     = (const float*)d_in[1];
    const float* qk_gamma = (const float*)d_in[2];
    const float* qk_beta  = (const float*)d_in[3];
    const float* qk_mean  = (const float*)d_in[4];
    const float* qk_var   = (const float*)d_in[5];
    const float* pe_w     = (const float*)d_in[6];
    const float* pe_gamma = (const float*)d_in[7];
    const float* pe_beta  = (const float*)d_in[8];
    const float* pe_mean  = (const float*)d_in[9];
    const float* pe_var   = (const float*)d_in[10];
    float* out = (float*)d_out;

    float* ws      = (float*)d_ws;
    float* kbuf    = ws;
    ushort* qf     = (ushort*)(ws + QF_OFF);
    float* kv_part = ws + KVP_OFF;
    ushort* kvt_h  = (ushort*)(ws + KVT_OFF);
    ushort* kvt_l  = kvt_h + 96 * 5120;
    ushort* whp    = (ushort*)(ws + WH_OFF);
    ushort* wlp    = whp + WSPLIT_N;

    hipLaunchKernelGGL(p0_wsplit, dim3((WSPLIT_N + 255)/256), dim3(256), 0, stream,
                       qk_w, whp, wlp);
    dim3 g1(49, 32, 3);
    hipLaunchKernelGGL(k1_qk_mfma, g1, dim3(256), 0, stream,
                       x, whp, wlp, qk_gamma, qk_beta, qk_mean, qk_var, kbuf, qf);
    dim3 g2(7, 6, 16);
    hipLaunchKernelGGL(k2_kv_mfma, g2, dim3(256), 0, stream, x, kbuf, kv_part);
    hipLaunchKernelGGL(k2b_reduce, dim3(96), dim3(256), 0, stream,
                       kv_part, kvt_h, kvt_l);
    dim3 g3(7, 6, 16);
    hipLaunchKernelGGL(k3_attn_pe, g3, dim3(256), 0, stream,
                       x, qf, kvt_h, kvt_l, pe_w, pe_gamma, pe_beta, pe_mean, pe_var, out);
}